// Round 2
// baseline (113.919 us; speedup 1.0000x reference)
//
#include <hip/hip_runtime.h>
#include <math.h>

// Problem constants
#define NB    256           // N nodes
#define FINN  32            // Fin
#define FOUTN 32            // Fout
#define BT    128           // B*T

// One GEMM: C[i,(bt,o)] = H[i,(e,j)] @ y2[(e,j),(bt,o)],  M=256 N=4096 K=4096.
// Block = (btq, oh, kq): 4 bt x 16 o x 1024 K. H staged LDS (shared across the
// 4-bt N-tile -> 128 MiB total L2 A-traffic); y2 produced IN-LDS exactly once
// globally (1.07 GF, no HBM round-trip); f32 K-partials (16 MiB, L3) reduced
// in an epilogue that adds the x@node_w MFMA + bias and applies gelu.

typedef __attribute__((ext_vector_type(8))) short short8;   // 8 bf16 = 4 VGPRs
typedef __attribute__((ext_vector_type(4))) float floatx4;  // MFMA accumulator

#define MFMA16(a,b,c) __builtin_amdgcn_mfma_f32_16x16x32_bf16((a),(b),(c),0,0,0)

__device__ __forceinline__ float gelu_f(float v) {
    return 0.5f * v * (1.0f + erff(v * 0.70710678118654752f));
}
__device__ __forceinline__ ushort f2bf(float x) {
    union { float f; unsigned u; } v; v.f = x;
    unsigned r = (v.u + 0x7FFFu + ((v.u >> 16) & 1u)) >> 16;
    return (ushort)r;
}
__device__ __forceinline__ uint2 pack4(floatx4 d) {
    uint2 p;
    p.x = (unsigned)f2bf(d[0]) | ((unsigned)f2bf(d[1]) << 16);
    p.y = (unsigned)f2bf(d[2]) | ((unsigned)f2bf(d[3]) << 16);
    return p;
}

typedef __attribute__((address_space(1))) void gvoid_t;
typedef __attribute__((address_space(3))) void lvoid_t;
__device__ __forceinline__ void gload_lds16(const void* g, void* l) {
    // async global->LDS, 16B/lane; LDS dest = wave-uniform base + lane*16.
    __builtin_amdgcn_global_load_lds((gvoid_t*)g, (lvoid_t*)l, 16, 0, 0);
}

// ---------------------------------------------------------------------------
// prep_kernel, grid 289 x 256 thr:
//   [0,128):   Hf  = gelu(adj*w1+b1) in MFMA A-fragment order   (2 MiB)
//   [128,160): xaf = x in MFMA A-fragment order, bf16           (2 MiB)
//   [160,288): bias2g[bt][o] = node_b[o] + (sum_j x[bt,j,:]) @ b2
//   288:       w2f (B-frag order) + nwf (node_w B-frags)
// ---------------------------------------------------------------------------
__global__ __launch_bounds__(256) void prep_kernel(
        const float* __restrict__ x,   const float* __restrict__ adj,
        const float* __restrict__ w1,  const float* __restrict__ b1,
        const float* __restrict__ w2,  const float* __restrict__ b2,
        const float* __restrict__ node_w, const float* __restrict__ node_b,
        ushort* __restrict__ Hf, ushort* __restrict__ w2f,
        ushort* __restrict__ xaf, ushort* __restrict__ nwf,
        float* __restrict__ bias2g) {
    int bid = blockIdx.x;
    int tid = threadIdx.x;

    if (bid < 128) {                    // ---- Hf (verified h_kernel body) ----
        __shared__ float adjs[16][264];
        __shared__ float w1s[16], b1s[16];
        int it = bid & 15;
        int kq8 = bid >> 4;             // 0..7
        if (tid < 16) { w1s[tid] = w1[tid]; b1s[tid] = b1[tid]; }
        #pragma unroll
        for (int q = 0; q < 4; ++q) {
            int u = q * 256 + tid;
            int row = u >> 6, c4 = u & 63;
            *(float4*)&adjs[row][c4 * 4] =
                ((const float4*)(adj + ((size_t)it * 16 + row) * 256))[c4];
        }
        __syncthreads();
        #pragma unroll
        for (int q = 0; q < 4; ++q) {
            int u = q * 256 + tid;
            int ks = kq8 * 16 + (u >> 6);
            int lane = u & 63;
            int m = lane & 15, quad = lane >> 4;
            int e = ks >> 3;
            int j0 = (ks & 7) * 32 + quad * 8;
            float w = w1s[e], b = b1s[e];
            ushort tmp[8];
            #pragma unroll
            for (int d = 0; d < 8; ++d)
                tmp[d] = f2bf(gelu_f(adjs[m][j0 + d] * w + b));
            *(int4*)(Hf + (((size_t)it * 128 + ks) * 64 + lane) * 8) = *(int4*)tmp;
        }
        return;
    }
    if (bid < 160) {                    // ---- xaf: wave -> one bt ----
        int wv = tid >> 6, lane = tid & 63, m = lane & 15, quad = lane >> 4;
        int bt = (bid - 128) * 4 + wv;
        #pragma unroll
        for (int jt = 0; jt < 16; ++jt) {
            const float* xs = x + ((size_t)bt * NB + jt * 16 + m) * FINN + quad * 8;
            float4 lo = *(const float4*)xs;
            float4 hi = *(const float4*)(xs + 4);
            ushort tmp[8];
            tmp[0]=f2bf(lo.x); tmp[1]=f2bf(lo.y); tmp[2]=f2bf(lo.z); tmp[3]=f2bf(lo.w);
            tmp[4]=f2bf(hi.x); tmp[5]=f2bf(hi.y); tmp[6]=f2bf(hi.z); tmp[7]=f2bf(hi.w);
            *(int4*)(xaf + (((size_t)bt * 16 + jt) * 64 + lane) * 8) = *(int4*)tmp;
        }
        return;
    }
    if (bid < 288) {                    // ---- bias2g (verified logic) ----
        __shared__ float Sp[8][32];
        __shared__ float Svs[32];
        int bt = bid - 160;
        int f = tid & 31, grp = tid >> 5;
        float s = 0.f;
        for (int j = grp; j < NB; j += 8)
            s += x[((size_t)bt * NB + j) * FINN + f];
        Sp[grp][f] = s;
        __syncthreads();
        if (tid < 32) {
            float s2 = 0.f;
            #pragma unroll
            for (int g = 0; g < 8; ++g) s2 += Sp[g][tid];
            Svs[tid] = s2;
        }
        __syncthreads();
        if (tid < 32) {
            float bb = node_b[tid];
            #pragma unroll
            for (int f2 = 0; f2 < FINN; ++f2)
                bb += Svs[f2] * b2[f2 * FOUTN + tid];
            bias2g[bt * 32 + tid] = bb;
        }
        return;
    }
    // ---- bid == 288: w2f (verified round-0 layout) + nwf ----
    for (int s = 0; s < 2048; s += 256) {
        int slot = s + tid;             // (e*2+ot)*64 + lane
        int e = slot >> 7, r = slot & 127;
        int ot = r >> 6, lane = r & 63;
        int m = lane & 15, quad = lane >> 4;
        const float* src = w2 + (size_t)e * 1024 + (quad * 8) * 32 + ot * 16 + m;
        ushort tmp[8];
        #pragma unroll
        for (int i = 0; i < 8; ++i) tmp[i] = f2bf(src[i * 32]);
        *(int4*)(w2f + (size_t)slot * 8) = *(int4*)tmp;
    }
    if (tid < 128) {
        int ot = tid >> 6, lane = tid & 63, m = lane & 15, q = lane >> 4;
        ushort tmp[8];
        #pragma unroll
        for (int d = 0; d < 8; ++d)
            tmp[d] = f2bf(node_w[(q * 8 + d) * 32 + ot * 16 + m]);
        *(int4*)(nwf + tid * 8) = *(int4*)tmp;
    }
}

// ---------------------------------------------------------------------------
// main_kernel: grid (32 btq, 2 oh, 4 kq) x 512 thr (8 waves), 1 block/CU.
// Per chunk (2 k-slices): stage H-frags (32 KiB, gload_lds, dbuf) + produce
// y2 B-frags in-LDS (2 MFMA/wave, dbuf) + consume (2 kk x {2 A + 4 B ds_read,
// 8 MFMA}/wave) + one __syncthreads. 16 chunks. Partials -> Cp f32.
// Roles: production wave w -> bt=w&3, j-half=w>>2; consumption wave w ->
// i-tiles {2w, 2w+1}. All LDS access linear lane*16B (conflict-free).
// ---------------------------------------------------------------------------
__global__ __launch_bounds__(512, 1) void main_kernel(
        const ushort* __restrict__ Hf,  const ushort* __restrict__ w2f,
        const ushort* __restrict__ xaf, float* __restrict__ Cp) {
    __shared__ ushort Asl[2][2][16][512];   // 64 KiB [buf][ksL][it][frag]
    __shared__ ushort Bsl[2][2][4][512];    // 16 KiB [buf][ksL][btL][frag]

    int btq  = blockIdx.x;              // 0..31
    int oh   = blockIdx.y;              // 0..1
    int kq   = blockIdx.z;              // 0..3
    int tid  = threadIdx.x;
    int wv   = tid >> 6;                // 0..7
    int lane = tid & 63;
    int m    = lane & 15;
    int quad = lane >> 4;

    // production role
    int pbt = wv & 3;                   // local bt 0..3
    int pjh = wv >> 2;                  // j-half 0/1
    int btg = btq * 4 + pbt;

    // x A-frags for this wave's production slots (jt = p*2 + pjh), registers
    short8 xfr[8];
    #pragma unroll
    for (int p = 0; p < 8; ++p)
        xfr[p] = *(const short8*)(xaf + (((size_t)btg * 16 + p * 2 + pjh) * 64 + lane) * 8);

    floatx4 acc[2][4] = {};

    #define STAGE_A(buf, c)                                                   \
    {                                                                         \
        _Pragma("unroll")                                                     \
        for (int s = 0; s < 4; ++s) {                                         \
            int fid = s * 8 + wv;       /* 32 frags: [ksL][it] */             \
            int itA = fid & 15, ksL = fid >> 4;                               \
            int ksg = kq * 32 + (c) * 2 + ksL;                                \
            gload_lds16(Hf + (((size_t)itA * 128 + ksg) * 64 + lane) * 8,     \
                        &Asl[buf][ksL][itA][lane * 8]);                       \
        }                                                                     \
    }
    #define PRODUCE(buf, c)                                                   \
    {                                                                         \
        _Pragma("unroll")                                                     \
        for (int s = 0; s < 2; ++s) {                                         \
            int ksg = kq * 32 + (c) * 2 + s;                                  \
            int e = ksg >> 3, p = ksg & 7;                                    \
            short8 wf = *(const short8*)(w2f + (size_t)e * 1024 + oh * 512 + lane * 8); \
            floatx4 z = {0.f, 0.f, 0.f, 0.f};                                 \
            floatx4 d = MFMA16(xfr[p], wf, z);                                \
            int qc = pjh * 2 + (quad >> 1), dp = (quad & 1) * 4;              \
            *(uint2*)&Bsl[buf][s][pbt][(qc * 16 + m) * 8 + dp] = pack4(d);    \
        }                                                                     \
    }
    #define GEMMC(buf)                                                        \
    {                                                                         \
        _Pragma("unroll")                                                     \
        for (int kk = 0; kk < 2; ++kk) {                                      \
            short8 a0 = *(const short8*)&Asl[buf][kk][wv * 2 + 0][lane * 8];  \
            short8 a1 = *(const short8*)&Asl[buf][kk][wv * 2 + 1][lane * 8];  \
            _Pragma("unroll")                                                 \
            for (int bb = 0; bb < 4; ++bb) {                                  \
                short8 b = *(const short8*)&Bsl[buf][kk][bb][lane * 8];       \
                acc[0][bb] = MFMA16(a0, b, acc[0][bb]);                       \
                acc[1][bb] = MFMA16(a1, b, acc[1][bb]);                       \
            }                                                                 \
        }                                                                     \
    }

    STAGE_A(0, 0);
    PRODUCE(0, 0);
    __syncthreads();                    // drains vmcnt (stage-0) + lgkm
    #pragma unroll
    for (int c = 0; c < 16; ++c) {
        if (c < 15) {
            STAGE_A((c + 1) & 1, c + 1);
            PRODUCE((c + 1) & 1, c + 1);
        }
        GEMMC(c & 1);
        __syncthreads();                // buf-reuse guard + next-stage drain
    }

    // ---- store f32 K-partials: Cp[kq][bt][i][o] ----
    #pragma unroll
    for (int t = 0; t < 2; ++t) {
        #pragma unroll
        for (int bb = 0; bb < 4; ++bb) {
            #pragma unroll
            for (int r = 0; r < 4; ++r) {
                int i = (wv * 2 + t) * 16 + quad * 4 + r;
                Cp[(((size_t)kq * BT + btq * 4 + bb) * NB + i) * FOUTN + oh * 16 + m]
                    = acc[t][bb][r];
            }
        }
    }
    #undef STAGE_A
    #undef PRODUCE
    #undef GEMMC
}

// ---------------------------------------------------------------------------
// epilogue: grid 128 (bt) x 256 thr. out = gelu(sum_kq Cp + x@node_w + bias2).
// ---------------------------------------------------------------------------
__global__ __launch_bounds__(256) void epi_kernel(
        const ushort* __restrict__ xaf, const ushort* __restrict__ nwf,
        const float* __restrict__ bias2g, const float* __restrict__ Cp,
        float* __restrict__ out) {
    int bt   = blockIdx.x;
    int tid  = threadIdx.x;
    int wv   = tid >> 6;
    int lane = tid & 63;
    int m    = lane & 15;
    int quad = lane >> 4;

    short8 nb0 = *(const short8*)(nwf + (size_t)lane * 8);
    short8 nb1 = *(const short8*)(nwf + ((size_t)64 + lane) * 8);

    #pragma unroll
    for (int t = 0; t < 4; ++t) {
        int it = wv * 4 + t;
        short8 xa = *(const short8*)(xaf + (((size_t)bt * 16 + it) * 64 + lane) * 8);
        #pragma unroll
        for (int tn = 0; tn < 2; ++tn) {
            floatx4 z = {0.f, 0.f, 0.f, 0.f};
            floatx4 ea = MFMA16(xa, tn ? nb1 : nb0, z);
            float bz = bias2g[bt * 32 + tn * 16 + m];
            #pragma unroll
            for (int r = 0; r < 4; ++r) {
                int i = it * 16 + quad * 4 + r;
                float s = ea[r] + bz;
                #pragma unroll
                for (int kqi = 0; kqi < 4; ++kqi)
                    s += Cp[(((size_t)kqi * BT + bt) * NB + i) * FOUTN + tn * 16 + m];
                out[((size_t)bt * NB + i) * FOUTN + tn * 16 + m] = gelu_f(s);
            }
        }
    }
}

// ---------------------------------------------------------------------------
extern "C" void kernel_launch(void* const* d_in, const int* in_sizes, int n_in,
                              void* d_out, int out_size, void* d_ws, size_t ws_size,
                              hipStream_t stream) {
    const float* x      = (const float*)d_in[0];
    const float* adj    = (const float*)d_in[1];
    const float* w1     = (const float*)d_in[2];
    const float* b1     = (const float*)d_in[3];
    const float* w2     = (const float*)d_in[4];
    const float* b2     = (const float*)d_in[5];
    const float* node_w = (const float*)d_in[6];
    const float* node_b = (const float*)d_in[7];
    float* out = (float*)d_out;

    // Workspace (~20.1 MiB):
    ushort* Hf     = (ushort*)d_ws;                  // 16*128*512  = 2 MiB
    ushort* w2f    = Hf + (size_t)16 * 128 * 512;    // 16*2*512    = 32 KiB
    ushort* xaf    = w2f + 16384;                    // 128*16*512  = 2 MiB
    ushort* nwf    = xaf + (size_t)128 * 16 * 512;   // 2*512       = 2 KiB
    float*  bias2g = (float*)(nwf + 1024);           // 128*32      = 16 KiB
    float*  Cp     = bias2g + 128 * 32;              // 4*128*256*32= 16 MiB

    hipLaunchKernelGGL(prep_kernel, dim3(289), dim3(256), 0, stream,
                       x, adj, w1, b1, w2, b2, node_w, node_b,
                       Hf, w2f, xaf, nwf, bias2g);
    hipLaunchKernelGGL(main_kernel, dim3(32, 2, 4), dim3(512), 0, stream,
                       Hf, w2f, xaf, Cp);
    hipLaunchKernelGGL(epi_kernel, dim3(BT), dim3(256), 0, stream,
                       xaf, nwf, bias2g, Cp, out);
}

// Round 3
// 109.934 us; speedup vs baseline: 1.0363x; 1.0363x over previous
//
#include <hip/hip_runtime.h>
#include <math.h>

// Problem constants
#define NB    256           // N nodes
#define FINN  32            // Fin
#define FOUTN 32            // Fout
#define BT    128           // B*T

// One GEMM: C[i,(bt,o)] = H[i,(e,j)] @ y2[(e,j),(bt,o)],  M=256 N=4096 K=4096.
// Block (bt,kq): all 256 i x 32 o x K-quarter (4 e = 32 ks). y2 produced
// IN-LDS exactly once globally (block owns its (bt, e-range)); B-frags stored
// fragment-linear (lane*16B reads, conflict-free); A-frags register-prefetched
// from L2-resident Hf; raw lgkm barriers keep prefetch in flight. f32
// K-partials (16 MiB, L3) reduced by the verified epilogue.

typedef __attribute__((ext_vector_type(8))) short short8;   // 8 bf16 = 4 VGPRs
typedef __attribute__((ext_vector_type(4))) float floatx4;  // MFMA accumulator

#define MFMA16(a,b,c) __builtin_amdgcn_mfma_f32_16x16x32_bf16((a),(b),(c),0,0,0)

// LDS-ordering-only barrier: does NOT drain in-flight global register loads
// (A-prefetch survives across windows). Bs producer->consumer needs lgkm only.
#define BARRIER() asm volatile("s_waitcnt lgkmcnt(0)\n\ts_barrier" ::: "memory")

__device__ __forceinline__ float gelu_f(float v) {
    return 0.5f * v * (1.0f + erff(v * 0.70710678118654752f));
}
__device__ __forceinline__ ushort f2bf(float x) {
    union { float f; unsigned u; } v; v.f = x;
    unsigned r = (v.u + 0x7FFFu + ((v.u >> 16) & 1u)) >> 16;
    return (ushort)r;
}
__device__ __forceinline__ float bf2f(ushort b) {
    union { unsigned u; float f; } v; v.u = ((unsigned)b) << 16; return v.f;
}
__device__ __forceinline__ uint2 pack4(floatx4 d) {
    uint2 p;
    p.x = (unsigned)f2bf(d[0]) | ((unsigned)f2bf(d[1]) << 16);
    p.y = (unsigned)f2bf(d[2]) | ((unsigned)f2bf(d[3]) << 16);
    return p;
}

// ---------------------------------------------------------------------------
// prep_kernel, grid 289 x 256 thr (verified round-2 code, verbatim):
//   [0,128):   Hf  = gelu(adj*w1+b1) in MFMA A-fragment order   (2 MiB)
//   [128,160): xaf = x in MFMA A-fragment order, bf16           (2 MiB)
//   [160,288): bias2g[bt][o] = node_b[o] + (sum_j x[bt,j,:]) @ b2
//   288:       w2f (B-frag order) + nwf (node_w B-frags)
// ---------------------------------------------------------------------------
__global__ __launch_bounds__(256) void prep_kernel(
        const float* __restrict__ x,   const float* __restrict__ adj,
        const float* __restrict__ w1,  const float* __restrict__ b1,
        const float* __restrict__ w2,  const float* __restrict__ b2,
        const float* __restrict__ node_w, const float* __restrict__ node_b,
        ushort* __restrict__ Hf, ushort* __restrict__ w2f,
        ushort* __restrict__ xaf, ushort* __restrict__ nwf,
        float* __restrict__ bias2g) {
    int bid = blockIdx.x;
    int tid = threadIdx.x;

    if (bid < 128) {                    // ---- Hf ----
        __shared__ float adjs[16][264];
        __shared__ float w1s[16], b1s[16];
        int it = bid & 15;
        int kq8 = bid >> 4;             // 0..7
        if (tid < 16) { w1s[tid] = w1[tid]; b1s[tid] = b1[tid]; }
        #pragma unroll
        for (int q = 0; q < 4; ++q) {
            int u = q * 256 + tid;
            int row = u >> 6, c4 = u & 63;
            *(float4*)&adjs[row][c4 * 4] =
                ((const float4*)(adj + ((size_t)it * 16 + row) * 256))[c4];
        }
        __syncthreads();
        #pragma unroll
        for (int q = 0; q < 4; ++q) {
            int u = q * 256 + tid;
            int ks = kq8 * 16 + (u >> 6);
            int lane = u & 63;
            int m = lane & 15, quad = lane >> 4;
            int e = ks >> 3;
            int j0 = (ks & 7) * 32 + quad * 8;
            float w = w1s[e], b = b1s[e];
            ushort tmp[8];
            #pragma unroll
            for (int d = 0; d < 8; ++d)
                tmp[d] = f2bf(gelu_f(adjs[m][j0 + d] * w + b));
            *(int4*)(Hf + (((size_t)it * 128 + ks) * 64 + lane) * 8) = *(int4*)tmp;
        }
        return;
    }
    if (bid < 160) {                    // ---- xaf: wave -> one bt ----
        int wv = tid >> 6, lane = tid & 63, m = lane & 15, quad = lane >> 4;
        int bt = (bid - 128) * 4 + wv;
        #pragma unroll
        for (int jt = 0; jt < 16; ++jt) {
            const float* xs = x + ((size_t)bt * NB + jt * 16 + m) * FINN + quad * 8;
            float4 lo = *(const float4*)xs;
            float4 hi = *(const float4*)(xs + 4);
            ushort tmp[8];
            tmp[0]=f2bf(lo.x); tmp[1]=f2bf(lo.y); tmp[2]=f2bf(lo.z); tmp[3]=f2bf(lo.w);
            tmp[4]=f2bf(hi.x); tmp[5]=f2bf(hi.y); tmp[6]=f2bf(hi.z); tmp[7]=f2bf(hi.w);
            *(int4*)(xaf + (((size_t)bt * 16 + jt) * 64 + lane) * 8) = *(int4*)tmp;
        }
        return;
    }
    if (bid < 288) {                    // ---- bias2g ----
        __shared__ float Sp[8][32];
        __shared__ float Svs[32];
        int bt = bid - 160;
        int f = tid & 31, grp = tid >> 5;
        float s = 0.f;
        for (int j = grp; j < NB; j += 8)
            s += x[((size_t)bt * NB + j) * FINN + f];
        Sp[grp][f] = s;
        __syncthreads();
        if (tid < 32) {
            float s2 = 0.f;
            #pragma unroll
            for (int g = 0; g < 8; ++g) s2 += Sp[g][tid];
            Svs[tid] = s2;
        }
        __syncthreads();
        if (tid < 32) {
            float bb = node_b[tid];
            #pragma unroll
            for (int f2 = 0; f2 < FINN; ++f2)
                bb += Svs[f2] * b2[f2 * FOUTN + tid];
            bias2g[bt * 32 + tid] = bb;
        }
        return;
    }
    // ---- bid == 288: w2f + nwf ----
    for (int s = 0; s < 2048; s += 256) {
        int slot = s + tid;             // (e*2+ot)*64 + lane
        int e = slot >> 7, r = slot & 127;
        int ot = r >> 6, lane = r & 63;
        int m = lane & 15, quad = lane >> 4;
        const float* src = w2 + (size_t)e * 1024 + (quad * 8) * 32 + ot * 16 + m;
        ushort tmp[8];
        #pragma unroll
        for (int i = 0; i < 8; ++i) tmp[i] = f2bf(src[i * 32]);
        *(int4*)(w2f + (size_t)slot * 8) = *(int4*)tmp;
    }
    if (tid < 128) {
        int ot = tid >> 6, lane = tid & 63, m = lane & 15, q = lane >> 4;
        ushort tmp[8];
        #pragma unroll
        for (int d = 0; d < 8; ++d)
            tmp[d] = f2bf(node_w[(q * 8 + d) * 32 + ot * 16 + m]);
        *(int4*)(nwf + tid * 8) = *(int4*)tmp;
    }
}

// ---------------------------------------------------------------------------
// main_kernel: grid (128 bt, 4 kq) x 512 thr (8 waves), 2 blocks/CU = 16
// waves/CU. 4 windows (1 e each). Per window: produce next window's y2 frags
// in-LDS (4 MFMA/wave, fragment-linear dbuf), consume 8 kk x {2 A-prefetch
// (global, in flight across barriers), 2 linear ds_read_b128, 4 MFMA}, one
// raw lgkm barrier. Wave roles: produce jt in {wv, wv+8}; consume it in
// {2wv, 2wv+1}. Partials -> Cp f32 [kq][bt][i][o].
// ---------------------------------------------------------------------------
__global__ __launch_bounds__(512, 4) void main_kernel(
        const ushort* __restrict__ Hf,  const ushort* __restrict__ w2f,
        const ushort* __restrict__ xaf, float* __restrict__ Cp) {
    __shared__ ushort Bsl[2][8][2][512];    // 32 KiB [buf][jp][oh][frag]

    int bt   = blockIdx.x;              // 0..127
    int kq   = blockIdx.y;              // 0..3
    int tid  = threadIdx.x;
    int wv   = tid >> 6;                // 0..7
    int lane = tid & 63;
    int m    = lane & 15;
    int quad = lane >> 4;

    // produce inputs: x A-frags for jt = wv, wv+8; w2 B-frags for all 4 e
    short8 xfr[2];
    #pragma unroll
    for (int t = 0; t < 2; ++t)
        xfr[t] = *(const short8*)(xaf + (((size_t)bt * 16 + wv + 8 * t) * 64 + lane) * 8);
    short8 wfr[4][2];
    #pragma unroll
    for (int e_ = 0; e_ < 4; ++e_)
        #pragma unroll
        for (int ot = 0; ot < 2; ++ot)
            wfr[e_][ot] = *(const short8*)(w2f + (size_t)(kq * 4 + e_) * 1024
                                           + ot * 512 + lane * 8);

    short8 areg[2][2];                  // A-prefetch ping-pong [s&1][it-sub]
    floatx4 acc[2][2] = {};             // [it-sub][oh]

    #define ALOADS(pp, s_)                                                    \
    {                                                                         \
        int ks_ = kq * 32 + (s_);                                             \
        areg[pp][0] = *(const short8*)(Hf + (((size_t)(2 * wv + 0) * 128 + ks_) * 64 + lane) * 8); \
        areg[pp][1] = *(const short8*)(Hf + (((size_t)(2 * wv + 1) * 128 + ks_) * 64 + lane) * 8); \
    }
    // Produce window w_: D[j][o] for e = kq*4+w_, scatter into B-frag order
    // (qc/dp formula verified rounds 0-2, bit-identical absmax).
    #define PRODUCE(buf, w_)                                                  \
    {                                                                         \
        int qc = (wv & 1) * 2 + (quad >> 1);                                  \
        int dp = (quad & 1) * 4;                                              \
        _Pragma("unroll")                                                     \
        for (int t = 0; t < 2; ++t) {                                         \
            int jp = (wv >> 1) + 4 * t;                                       \
            floatx4 z = {0.f, 0.f, 0.f, 0.f};                                 \
            floatx4 d0 = MFMA16(xfr[t], wfr[w_][0], z);                       \
            floatx4 d1 = MFMA16(xfr[t], wfr[w_][1], z);                       \
            *(uint2*)&Bsl[buf][jp][0][(qc * 16 + m) * 8 + dp] = pack4(d0);    \
            *(uint2*)&Bsl[buf][jp][1][(qc * 16 + m) * 8 + dp] = pack4(d1);    \
        }                                                                     \
    }
    #define GEMMC(buf, w_)                                                    \
    {                                                                         \
        _Pragma("unroll")                                                     \
        for (int kk = 0; kk < 8; ++kk) {                                      \
            int s = (w_) * 8 + kk;                                            \
            if (s < 31) ALOADS((s + 1) & 1, s + 1);                           \
            short8 b0 = *(const short8*)&Bsl[buf][kk][0][lane * 8];           \
            short8 b1 = *(const short8*)&Bsl[buf][kk][1][lane * 8];           \
            acc[0][0] = MFMA16(areg[s & 1][0], b0, acc[0][0]);                \
            acc[0][1] = MFMA16(areg[s & 1][0], b1, acc[0][1]);                \
            acc[1][0] = MFMA16(areg[s & 1][1], b0, acc[1][0]);                \
            acc[1][1] = MFMA16(areg[s & 1][1], b1, acc[1][1]);                \
        }                                                                     \
    }

    ALOADS(0, 0);                       // prefetch s=0
    PRODUCE(0, 0);
    BARRIER();                          // buf0 ready (lgkm only)
    #pragma unroll
    for (int w = 0; w < 4; ++w) {
        if (w < 3) PRODUCE((w + 1) & 1, w + 1);
        GEMMC(w & 1, w);
        BARRIER();                      // next buf ready; A-loads stay in flight
    }

    // ---- store f32 K-partials: Cp[kq][bt][i][o] ----
    #pragma unroll
    for (int t = 0; t < 2; ++t)
        #pragma unroll
        for (int oh = 0; oh < 2; ++oh)
            #pragma unroll
            for (int r = 0; r < 4; ++r) {
                int i = (2 * wv + t) * 16 + quad * 4 + r;
                Cp[(((size_t)kq * BT + bt) * NB + i) * FOUTN + oh * 16 + m]
                    = acc[t][oh][r];
            }
    #undef ALOADS
    #undef PRODUCE
    #undef GEMMC
}

// ---------------------------------------------------------------------------
// epilogue (verified round-2 code, verbatim): grid 128 (bt) x 256 thr.
// out = gelu(sum_kq Cp + x@node_w + bias2).
// ---------------------------------------------------------------------------
__global__ __launch_bounds__(256) void epi_kernel(
        const ushort* __restrict__ xaf, const ushort* __restrict__ nwf,
        const float* __restrict__ bias2g, const float* __restrict__ Cp,
        float* __restrict__ out) {
    int bt   = blockIdx.x;
    int tid  = threadIdx.x;
    int wv   = tid >> 6;
    int lane = tid & 63;
    int m    = lane & 15;
    int quad = lane >> 4;

    short8 nb0 = *(const short8*)(nwf + (size_t)lane * 8);
    short8 nb1 = *(const short8*)(nwf + ((size_t)64 + lane) * 8);

    #pragma unroll
    for (int t = 0; t < 4; ++t) {
        int it = wv * 4 + t;
        short8 xa = *(const short8*)(xaf + (((size_t)bt * 16 + it) * 64 + lane) * 8);
        #pragma unroll
        for (int tn = 0; tn < 2; ++tn) {
            floatx4 z = {0.f, 0.f, 0.f, 0.f};
            floatx4 ea = MFMA16(xa, tn ? nb1 : nb0, z);
            float bz = bias2g[bt * 32 + tn * 16 + m];
            #pragma unroll
            for (int r = 0; r < 4; ++r) {
                int i = it * 16 + quad * 4 + r;
                float s = ea[r] + bz;
                #pragma unroll
                for (int kqi = 0; kqi < 4; ++kqi)
                    s += Cp[(((size_t)kqi * BT + bt) * NB + i) * FOUTN + tn * 16 + m];
                out[((size_t)bt * NB + i) * FOUTN + tn * 16 + m] = gelu_f(s);
            }
        }
    }
}

// ---------------------------------------------------------------------------
extern "C" void kernel_launch(void* const* d_in, const int* in_sizes, int n_in,
                              void* d_out, int out_size, void* d_ws, size_t ws_size,
                              hipStream_t stream) {
    const float* x      = (const float*)d_in[0];
    const float* adj    = (const float*)d_in[1];
    const float* w1     = (const float*)d_in[2];
    const float* b1     = (const float*)d_in[3];
    const float* w2     = (const float*)d_in[4];
    const float* b2     = (const float*)d_in[5];
    const float* node_w = (const float*)d_in[6];
    const float* node_b = (const float*)d_in[7];
    float* out = (float*)d_out;

    // Workspace (~20.1 MiB):
    ushort* Hf     = (ushort*)d_ws;                  // 16*128*512  = 2 MiB
    ushort* w2f    = Hf + (size_t)16 * 128 * 512;    // 16*2*512    = 32 KiB
    ushort* xaf    = w2f + 16384;                    // 128*16*512  = 2 MiB
    ushort* nwf    = xaf + (size_t)128 * 16 * 512;   // 2*512       = 2 KiB
    float*  bias2g = (float*)(nwf + 1024);           // 128*32      = 16 KiB
    float*  Cp     = bias2g + 128 * 32;              // 4*128*256*32= 16 MiB

    hipLaunchKernelGGL(prep_kernel, dim3(289), dim3(256), 0, stream,
                       x, adj, w1, b1, w2, b2, node_w, node_b,
                       Hf, w2f, xaf, nwf, bias2g);
    hipLaunchKernelGGL(main_kernel, dim3(BT, 4), dim3(512), 0, stream,
                       Hf, w2f, xaf, Cp);
    hipLaunchKernelGGL(epi_kernel, dim3(BT), dim3(256), 0, stream,
                       xaf, nwf, bias2g, Cp, out);
}

// Round 4
// 104.558 us; speedup vs baseline: 1.0895x; 1.0514x over previous
//
#include <hip/hip_runtime.h>
#include <math.h>

// Problem constants
#define NB    256           // N nodes
#define FINN  32            // Fin
#define FOUTN 32            // Fout
#define BT    128           // B*T

// One GEMM: C[i,(bt,o)] = H[i,(e,j)] @ y2[(e,j),(bt,o)],  M=256 N=4096 K=4096.
// Block (bt,kq): all 256 i x 32 o x K-quarter (4 e = 32 ks). y2 produced
// IN-LDS exactly once globally; B-frags fragment-linear (conflict-free);
// A-frags register-prefetched (distance 2) from L2-resident Hf; raw lgkm
// barriers keep prefetch in flight. Window loop is unroll-1 so register
// pressure stays bounded (no spills). f32 K-partials [bt][i][kq][o] reduced
// by the epilogue on grid (128,2).

typedef __attribute__((ext_vector_type(8))) short short8;   // 8 bf16 = 4 VGPRs
typedef __attribute__((ext_vector_type(4))) float floatx4;  // MFMA accumulator

#define MFMA16(a,b,c) __builtin_amdgcn_mfma_f32_16x16x32_bf16((a),(b),(c),0,0,0)

// LDS-ordering-only barrier: does NOT drain in-flight global register loads.
#define BARRIER() asm volatile("s_waitcnt lgkmcnt(0)\n\ts_barrier" ::: "memory")

__device__ __forceinline__ float gelu_f(float v) {
    return 0.5f * v * (1.0f + erff(v * 0.70710678118654752f));
}
__device__ __forceinline__ ushort f2bf(float x) {
    union { float f; unsigned u; } v; v.f = x;
    unsigned r = (v.u + 0x7FFFu + ((v.u >> 16) & 1u)) >> 16;
    return (ushort)r;
}
__device__ __forceinline__ uint2 pack4(floatx4 d) {
    uint2 p;
    p.x = (unsigned)f2bf(d[0]) | ((unsigned)f2bf(d[1]) << 16);
    p.y = (unsigned)f2bf(d[2]) | ((unsigned)f2bf(d[3]) << 16);
    return p;
}

// ---------------------------------------------------------------------------
// prep_kernel, grid 289 x 256 thr (verified round-2/3 code, verbatim):
//   [0,128):   Hf  = gelu(adj*w1+b1) in MFMA A-fragment order   (2 MiB)
//   [128,160): xaf = x in MFMA A-fragment order, bf16           (2 MiB)
//   [160,288): bias2g[bt][o] = node_b[o] + (sum_j x[bt,j,:]) @ b2
//   288:       w2f (B-frag order) + nwf (node_w B-frags)
// ---------------------------------------------------------------------------
__global__ __launch_bounds__(256) void prep_kernel(
        const float* __restrict__ x,   const float* __restrict__ adj,
        const float* __restrict__ w1,  const float* __restrict__ b1,
        const float* __restrict__ w2,  const float* __restrict__ b2,
        const float* __restrict__ node_w, const float* __restrict__ node_b,
        ushort* __restrict__ Hf, ushort* __restrict__ w2f,
        ushort* __restrict__ xaf, ushort* __restrict__ nwf,
        float* __restrict__ bias2g) {
    int bid = blockIdx.x;
    int tid = threadIdx.x;

    if (bid < 128) {                    // ---- Hf ----
        __shared__ float adjs[16][264];
        __shared__ float w1s[16], b1s[16];
        int it = bid & 15;
        int kq8 = bid >> 4;             // 0..7
        if (tid < 16) { w1s[tid] = w1[tid]; b1s[tid] = b1[tid]; }
        #pragma unroll
        for (int q = 0; q < 4; ++q) {
            int u = q * 256 + tid;
            int row = u >> 6, c4 = u & 63;
            *(float4*)&adjs[row][c4 * 4] =
                ((const float4*)(adj + ((size_t)it * 16 + row) * 256))[c4];
        }
        __syncthreads();
        #pragma unroll
        for (int q = 0; q < 4; ++q) {
            int u = q * 256 + tid;
            int ks = kq8 * 16 + (u >> 6);
            int lane = u & 63;
            int m = lane & 15, quad = lane >> 4;
            int e = ks >> 3;
            int j0 = (ks & 7) * 32 + quad * 8;
            float w = w1s[e], b = b1s[e];
            ushort tmp[8];
            #pragma unroll
            for (int d = 0; d < 8; ++d)
                tmp[d] = f2bf(gelu_f(adjs[m][j0 + d] * w + b));
            *(int4*)(Hf + (((size_t)it * 128 + ks) * 64 + lane) * 8) = *(int4*)tmp;
        }
        return;
    }
    if (bid < 160) {                    // ---- xaf: wave -> one bt ----
        int wv = tid >> 6, lane = tid & 63, m = lane & 15, quad = lane >> 4;
        int bt = (bid - 128) * 4 + wv;
        #pragma unroll
        for (int jt = 0; jt < 16; ++jt) {
            const float* xs = x + ((size_t)bt * NB + jt * 16 + m) * FINN + quad * 8;
            float4 lo = *(const float4*)xs;
            float4 hi = *(const float4*)(xs + 4);
            ushort tmp[8];
            tmp[0]=f2bf(lo.x); tmp[1]=f2bf(lo.y); tmp[2]=f2bf(lo.z); tmp[3]=f2bf(lo.w);
            tmp[4]=f2bf(hi.x); tmp[5]=f2bf(hi.y); tmp[6]=f2bf(hi.z); tmp[7]=f2bf(hi.w);
            *(int4*)(xaf + (((size_t)bt * 16 + jt) * 64 + lane) * 8) = *(int4*)tmp;
        }
        return;
    }
    if (bid < 288) {                    // ---- bias2g ----
        __shared__ float Sp[8][32];
        __shared__ float Svs[32];
        int bt = bid - 160;
        int f = tid & 31, grp = tid >> 5;
        float s = 0.f;
        for (int j = grp; j < NB; j += 8)
            s += x[((size_t)bt * NB + j) * FINN + f];
        Sp[grp][f] = s;
        __syncthreads();
        if (tid < 32) {
            float s2 = 0.f;
            #pragma unroll
            for (int g = 0; g < 8; ++g) s2 += Sp[g][tid];
            Svs[tid] = s2;
        }
        __syncthreads();
        if (tid < 32) {
            float bb = node_b[tid];
            #pragma unroll
            for (int f2 = 0; f2 < FINN; ++f2)
                bb += Svs[f2] * b2[f2 * FOUTN + tid];
            bias2g[bt * 32 + tid] = bb;
        }
        return;
    }
    // ---- bid == 288: w2f + nwf ----
    for (int s = 0; s < 2048; s += 256) {
        int slot = s + tid;             // (e*2+ot)*64 + lane
        int e = slot >> 7, r = slot & 127;
        int ot = r >> 6, lane = r & 63;
        int m = lane & 15, quad = lane >> 4;
        const float* src = w2 + (size_t)e * 1024 + (quad * 8) * 32 + ot * 16 + m;
        ushort tmp[8];
        #pragma unroll
        for (int i = 0; i < 8; ++i) tmp[i] = f2bf(src[i * 32]);
        *(int4*)(w2f + (size_t)slot * 8) = *(int4*)tmp;
    }
    if (tid < 128) {
        int ot = tid >> 6, lane = tid & 63, m = lane & 15, q = lane >> 4;
        ushort tmp[8];
        #pragma unroll
        for (int d = 0; d < 8; ++d)
            tmp[d] = f2bf(node_w[(q * 8 + d) * 32 + ot * 16 + m]);
        *(int4*)(nwf + tid * 8) = *(int4*)tmp;
    }
}

// ---------------------------------------------------------------------------
// main_kernel: grid (128 bt, 4 kq) x 512 thr (8 waves), 2 blocks/CU = 16
// waves/CU. 4 windows (1 e each), window loop unroll-1 (bounded registers).
// Per window: load next-window w2 frags (L2), 8 kk x {distance-2 A-prefetch,
// 2 linear ds_read_b128, 4 MFMA}, produce next window's y2 frags in-LDS
// (4 MFMA, fragment-linear dbuf), raw lgkm barrier. Partials -> Cp f32
// [bt][i][kq][o] (store-coalesced).
// ---------------------------------------------------------------------------
__global__ __launch_bounds__(512, 4) void main_kernel(
        const ushort* __restrict__ Hf,  const ushort* __restrict__ w2f,
        const ushort* __restrict__ xaf, float* __restrict__ Cp) {
    __shared__ ushort Bsl[2][8][2][512];    // 32 KiB [buf][jp][oh][frag]

    int bt   = blockIdx.x;              // 0..127
    int kq   = blockIdx.y;              // 0..3
    int tid  = threadIdx.x;
    int wv   = tid >> 6;                // 0..7
    int lane = tid & 63;
    int m    = lane & 15;
    int quad = lane >> 4;

    // produce inputs: x A-frags for jt = wv, wv+8 (verified mapping)
    short8 xfr[2];
    #pragma unroll
    for (int t = 0; t < 2; ++t)
        xfr[t] = *(const short8*)(xaf + (((size_t)bt * 16 + wv + 8 * t) * 64 + lane) * 8);
    const int qc = (wv & 1) * 2 + (quad >> 1);    // B-frag scatter coords
    const int dp = (quad & 1) * 4;
    const int jp0 = (wv >> 1);

    const ushort* Ha = Hf + ((size_t)(2 * wv + 0) * 128) * 512 + (size_t)lane * 8;
    const ushort* Hb = Hf + ((size_t)(2 * wv + 1) * 128) * 512 + (size_t)lane * 8;
    const ushort* Wl = w2f + (size_t)lane * 8;

    short8 areg[4][2];                  // distance-2 A-prefetch ring
    floatx4 acc[2][2] = {};             // [it-sub][oh]

    #define ALOADS(slot, s_)                                                  \
    {                                                                         \
        int ks_ = kq * 32 + (s_); if (ks_ > 127) ks_ = 127;                   \
        areg[slot][0] = *(const short8*)(Ha + (size_t)ks_ * 512);             \
        areg[slot][1] = *(const short8*)(Hb + (size_t)ks_ * 512);             \
    }
    // Produce into buffer bp (ushort* base) with w-frags wf0/wf1 (verified
    // scatter: jp = (wv>>1)+4t, qc/dp formula — bit-identical rounds 0-3).
    #define PRODUCE(bp, wf0, wf1)                                             \
    {                                                                         \
        _Pragma("unroll")                                                     \
        for (int t = 0; t < 2; ++t) {                                         \
            int jp = jp0 + 4 * t;                                             \
            floatx4 z = {0.f, 0.f, 0.f, 0.f};                                 \
            floatx4 d0 = MFMA16(xfr[t], wf0, z);                              \
            floatx4 d1 = MFMA16(xfr[t], wf1, z);                              \
            *(uint2*)((bp) + jp * 1024 +       (qc * 16 + m) * 8 + dp) = pack4(d0); \
            *(uint2*)((bp) + jp * 1024 + 512 + (qc * 16 + m) * 8 + dp) = pack4(d1); \
        }                                                                     \
    }

    // prologue: A s=0,1; produce window 0 into buf 0
    ALOADS(0, 0);
    ALOADS(1, 1);
    {
        short8 wf0 = *(const short8*)(Wl + (size_t)(kq * 4) * 1024);
        short8 wf1 = *(const short8*)(Wl + (size_t)(kq * 4) * 1024 + 512);
        PRODUCE((ushort*)Bsl, wf0, wf1);
    }
    BARRIER();

    #pragma unroll 1
    for (int w = 0; w < 4; ++w) {
        // next-window w2 frags (clamped dummy at w=3; L2-resident)
        int en = kq * 4 + ((w < 3) ? (w + 1) : 3);
        short8 wf0 = *(const short8*)(Wl + (size_t)en * 1024);
        short8 wf1 = *(const short8*)(Wl + (size_t)en * 1024 + 512);

        ushort* Bb = (ushort*)Bsl + (w & 1) * 8192;       // consume buf
        #pragma unroll
        for (int kk = 0; kk < 8; ++kk) {
            ALOADS((kk + 2) & 3, w * 8 + kk + 2);
            short8 b0 = *(const short8*)(Bb + kk * 1024 + lane * 8);
            short8 b1 = *(const short8*)(Bb + kk * 1024 + 512 + lane * 8);
            acc[0][0] = MFMA16(areg[kk & 3][0], b0, acc[0][0]);
            acc[0][1] = MFMA16(areg[kk & 3][0], b1, acc[0][1]);
            acc[1][0] = MFMA16(areg[kk & 3][1], b0, acc[1][0]);
            acc[1][1] = MFMA16(areg[kk & 3][1], b1, acc[1][1]);
        }
        if (w < 3) {
            ushort* Bn = (ushort*)Bsl + ((w + 1) & 1) * 8192;
            PRODUCE(Bn, wf0, wf1);
        }
        BARRIER();                      // A-loads stay in flight (lgkm only)
    }

    // ---- store f32 K-partials: Cp[bt][i][kq][o] (64B-coalesced) ----
    #pragma unroll
    for (int t = 0; t < 2; ++t)
        #pragma unroll
        for (int oh = 0; oh < 2; ++oh)
            #pragma unroll
            for (int r = 0; r < 4; ++r) {
                int i = (2 * wv + t) * 16 + quad * 4 + r;
                Cp[(((size_t)bt * NB + i) * 4 + kq) * FOUTN + oh * 16 + m]
                    = acc[t][oh][r];
            }
    #undef ALOADS
    #undef PRODUCE
}

// ---------------------------------------------------------------------------
// epilogue: grid (128 bt, 2 ih) x 256 thr — all 256 CUs.
// out = gelu(sum_kq Cp + x@node_w + bias2).  (verified math, new Cp layout)
// ---------------------------------------------------------------------------
__global__ __launch_bounds__(256) void epi_kernel(
        const ushort* __restrict__ xaf, const ushort* __restrict__ nwf,
        const float* __restrict__ bias2g, const float* __restrict__ Cp,
        float* __restrict__ out) {
    int bt   = blockIdx.x;
    int ih   = blockIdx.y;
    int tid  = threadIdx.x;
    int wv   = tid >> 6;
    int lane = tid & 63;
    int m    = lane & 15;
    int quad = lane >> 4;

    short8 nb0 = *(const short8*)(nwf + (size_t)lane * 8);
    short8 nb1 = *(const short8*)(nwf + ((size_t)64 + lane) * 8);

    #pragma unroll
    for (int t = 0; t < 2; ++t) {
        int it = ih * 8 + wv * 2 + t;
        short8 xa = *(const short8*)(xaf + (((size_t)bt * 16 + it) * 64 + lane) * 8);
        #pragma unroll
        for (int tn = 0; tn < 2; ++tn) {
            floatx4 z = {0.f, 0.f, 0.f, 0.f};
            floatx4 ea = MFMA16(xa, tn ? nb1 : nb0, z);
            float bz = bias2g[bt * 32 + tn * 16 + m];
            #pragma unroll
            for (int r = 0; r < 4; ++r) {
                int i = it * 16 + quad * 4 + r;
                float s = ea[r] + bz;
                #pragma unroll
                for (int kqi = 0; kqi < 4; ++kqi)
                    s += Cp[(((size_t)bt * NB + i) * 4 + kqi) * FOUTN + tn * 16 + m];
                out[((size_t)bt * NB + i) * FOUTN + tn * 16 + m] = gelu_f(s);
            }
        }
    }
}

// ---------------------------------------------------------------------------
extern "C" void kernel_launch(void* const* d_in, const int* in_sizes, int n_in,
                              void* d_out, int out_size, void* d_ws, size_t ws_size,
                              hipStream_t stream) {
    const float* x      = (const float*)d_in[0];
    const float* adj    = (const float*)d_in[1];
    const float* w1     = (const float*)d_in[2];
    const float* b1     = (const float*)d_in[3];
    const float* w2     = (const float*)d_in[4];
    const float* b2     = (const float*)d_in[5];
    const float* node_w = (const float*)d_in[6];
    const float* node_b = (const float*)d_in[7];
    float* out = (float*)d_out;

    // Workspace (~20.1 MiB):
    ushort* Hf     = (ushort*)d_ws;                  // 16*128*512  = 2 MiB
    ushort* w2f    = Hf + (size_t)16 * 128 * 512;    // 16*2*512    = 32 KiB
    ushort* xaf    = w2f + 16384;                    // 128*16*512  = 2 MiB
    ushort* nwf    = xaf + (size_t)128 * 16 * 512;   // 2*512       = 2 KiB
    float*  bias2g = (float*)(nwf + 1024);           // 128*32      = 16 KiB
    float*  Cp     = bias2g + 128 * 32;              // 128*256*4*32= 16 MiB

    hipLaunchKernelGGL(prep_kernel, dim3(289), dim3(256), 0, stream,
                       x, adj, w1, b1, w2, b2, node_w, node_b,
                       Hf, w2f, xaf, nwf, bias2g);
    hipLaunchKernelGGL(main_kernel, dim3(BT, 4), dim3(512), 0, stream,
                       Hf, w2f, xaf, Cp);
    hipLaunchKernelGGL(epi_kernel, dim3(BT, 2), dim3(256), 0, stream,
                       xaf, nwf, bias2g, Cp, out);
}